// Round 1
// baseline (138.225 us; speedup 1.0000x reference)
//
#include <hip/hip_runtime.h>
#include <stdint.h>

// ConvMemory: out[b,i,h,w] = sum_k memory[k,i]*softmax_k(unfold(x))[k, (h,w)]
// Rewritten as 3x3 conv over E=exp(x) (bf16, MFMA) divided by box-sum Z.
// NOTE: reference pads x with ZEROS before softmax -> padded taps contribute
// exp(0)=1 to numerator AND denominator. OOB taps are filled with 1.0.

#define Bn 8
#define Cn 64
#define Hn 128
#define Wn 128
#define OC 128
#define HW (Hn * Wn)

typedef __attribute__((ext_vector_type(8))) short bf16x8_t;
typedef __attribute__((ext_vector_type(4))) float f32x4_t;

__device__ inline unsigned short f2bf(float f) {
    union { float f; uint32_t u; } v; v.f = f;
    uint32_t u = v.u;
    u += 0x7fffu + ((u >> 16) & 1u);
    return (unsigned short)(u >> 16);
}
__device__ inline float bf2f(unsigned short h) {
    union { uint32_t u; float f; } v; v.u = ((uint32_t)h) << 16;
    return v.f;
}

// ---------------------------------------------------------------------------
// Kernel 1: reorder memory[576][128] -> Bt[n][k'] bf16, k' = (kh*3+kw)*64 + c
// (so 8 consecutive k' = 8 consecutive channels -> contiguous b-frag loads)
// ---------------------------------------------------------------------------
__global__ void prep_b(const float* __restrict__ mem, unsigned short* __restrict__ Bt) {
    int kin = blockIdx.x;   // 0..575  (= c*9 + q)
    int n = threadIdx.x;    // 0..127
    int c = kin / 9, q = kin % 9;
    Bt[n * 576 + q * 64 + c] = f2bf(mem[kin * OC + n]);
}

// ---------------------------------------------------------------------------
// Kernel 2: E = exp(x) as bf16 in NHWC layout Et[b][h][w][c] (LDS transpose),
// plus per-pixel channel sum S[b][h][w] (fp32, from the SAME bf16 values so
// numerator/denominator stay consistent).
// ---------------------------------------------------------------------------
__global__ __launch_bounds__(256) void exp_tr(const float* __restrict__ x,
                                              unsigned short* __restrict__ Et,
                                              float* __restrict__ S) {
    __shared__ __align__(16) unsigned short lds[128][72];  // [w][c], pad 64->72
    int bid = blockIdx.x;            // 0..1023 = (b,h)
    int b = bid >> 7, h = bid & 127;
    int t = threadIdx.x;

    int c = t >> 2, l4 = t & 3;
    const float* xp = x + ((size_t)(b * Cn + c) * Hn + h) * Wn;
#pragma unroll
    for (int i = 0; i < 8; i++) {
        int w = i * 16 + l4 * 4;
        float4 v = *(const float4*)(xp + w);
        lds[w + 0][c] = f2bf(__expf(v.x));
        lds[w + 1][c] = f2bf(__expf(v.y));
        lds[w + 2][c] = f2bf(__expf(v.z));
        lds[w + 3][c] = f2bf(__expf(v.w));
    }
    __syncthreads();

    // write Et: thread pair covers one pixel's 64 channels (128 B contiguous)
    {
        int w = t >> 1, c0 = (t & 1) * 32;
        uint4* dst = (uint4*)(Et + (((size_t)(b * Hn + h) * Wn + w) * 64 + c0));
        const uint4* src = (const uint4*)(&lds[w][c0]);
        dst[0] = src[0]; dst[1] = src[1]; dst[2] = src[2]; dst[3] = src[3];
    }
    // channel sum
    if (t < 128) {
        int w = t;
        float s = 0.f;
#pragma unroll
        for (int c2 = 0; c2 < 64; c2++) s += bf2f(lds[w][c2]);
        S[(size_t)(b * Hn + h) * Wn + w] = s;
    }
}

// ---------------------------------------------------------------------------
// Kernel 3: Zinv = 1 / (3x3 box of S), OOB neighbor contributes 64 * exp(0)=64
// ---------------------------------------------------------------------------
__global__ void boxz(const float* __restrict__ S, float* __restrict__ Zinv) {
    int p = blockIdx.x * 256 + threadIdx.x;  // 0..131071
    int b = p >> 14, r = p & 16383, h = r >> 7, w = r & 127;
    const float* Sp = S + (size_t)b * HW;
    float z = 0.f;
#pragma unroll
    for (int dh = -1; dh <= 1; dh++) {
        int hh = h + dh;
#pragma unroll
        for (int dw = -1; dw <= 1; dw++) {
            int ww = w + dw;
            if (hh >= 0 && hh < Hn && ww >= 0 && ww < Wn)
                z += Sp[hh * Wn + ww];
            else
                z += 64.0f;  // 64 channels of exp(0)=1
        }
    }
    Zinv[p] = 1.f / z;
}

// ---------------------------------------------------------------------------
// Kernel 4: implicit-GEMM 3x3 conv with mfma_f32_16x16x32_bf16.
// Block = 4x16 pixel tile. LDS E tile [6][18][72] (pad 64->72: 16B-aligned,
// 2-way-conflict-free b128 reads). K reordered (kh,kw,c): chunk kc (32 wide)
// = fixed (kh,kw)=q, channels c0..c0+31. Wave owns 2 N-tiles x 4 M-tiles.
// ---------------------------------------------------------------------------
__global__ __launch_bounds__(256) void conv_mfma(const unsigned short* __restrict__ Et,
                                                 const unsigned short* __restrict__ Bt,
                                                 const float* __restrict__ Zinv,
                                                 float* __restrict__ out) {
    __shared__ __align__(16) unsigned short lds[6 * 18 * 72];

    int bid = blockIdx.x;       // 2048 = 8 b * 32 ty * 8 tx
    int b = bid >> 8;
    int rem = bid & 255;
    int ty = rem >> 3;          // 0..31
    int tx = rem & 7;           // 0..7
    int h0 = ty * 4, w0 = tx * 16;
    int t = threadIdx.x;

    // stage E halo tile: pixels (h0-1..h0+4) x (w0-1..w0+16), OOB -> bf16(1.0)
    {
        int pp = t >> 3;              // 0..31
        int c0 = (t & 7) * 8;         // 0,8,..,56
        const uint4 ones = make_uint4(0x3F803F80u, 0x3F803F80u, 0x3F803F80u, 0x3F803F80u);
#pragma unroll
        for (int rr = 0; rr < 4; rr++) {
            int p = pp + rr * 32;
            if (p < 108) {
                int y = p / 18, xx = p % 18;
                int gh = h0 - 1 + y, gw = w0 - 1 + xx;
                uint4 v = ones;
                if (gh >= 0 && gh < Hn && gw >= 0 && gw < Wn)
                    v = *(const uint4*)(Et + (((size_t)(b * Hn + gh) * Wn + gw) * 64 + c0));
                *(uint4*)(&lds[(y * 18 + xx) * 72 + c0]) = v;
            }
        }
    }
    __syncthreads();

    int wave = t >> 6, lane = t & 63;
    int mcol = lane & 15;   // m for A, n-offset for B/D
    int quad = lane >> 4;
    int koff = quad * 8;

    f32x4_t acc[4][2];
#pragma unroll
    for (int i = 0; i < 4; i++)
#pragma unroll
        for (int j = 0; j < 2; j++) acc[i][j] = (f32x4_t){0.f, 0.f, 0.f, 0.f};

    int n_base = wave * 32;  // two n-tiles: n_base, n_base+16

    for (int kc = 0; kc < 18; kc++) {
        int q = kc >> 1;
        int c0 = (kc & 1) * 32;
        int kh = q / 3, kw = q % 3;

        bf16x8_t a[4];
#pragma unroll
        for (int tI = 0; tI < 4; tI++) {
            int addr = ((tI + kh) * 18 + (mcol + kw)) * 72 + c0 + koff;
            a[tI] = *(const bf16x8_t*)(&lds[addr]);
        }
        bf16x8_t bb[2];
#pragma unroll
        for (int nn = 0; nn < 2; nn++) {
            int n = n_base + nn * 16 + mcol;
            bb[nn] = *(const bf16x8_t*)(Bt + (n * 576 + q * 64 + c0 + koff));
        }
#pragma unroll
        for (int tI = 0; tI < 4; tI++)
#pragma unroll
            for (int nn = 0; nn < 2; nn++)
                acc[tI][nn] = __builtin_amdgcn_mfma_f32_16x16x32_bf16(a[tI], bb[nn], acc[tI][nn], 0, 0, 0);
    }

    // epilogue: D col = lane&15 (n), rows = quad*4 + r (pixel x-offset)
    int xoff = quad * 4;
#pragma unroll
    for (int tI = 0; tI < 4; tI++) {
        int hy = h0 + tI;
        f32x4_t zi = *(const f32x4_t*)(Zinv + ((size_t)b * HW + hy * Wn + w0 + xoff));
#pragma unroll
        for (int nn = 0; nn < 2; nn++) {
            int n = n_base + nn * 16 + mcol;
            f32x4_t v = acc[tI][nn] * zi;
            *(f32x4_t*)(out + (((size_t)(b * OC + n) * Hn + hy) * Wn + w0 + xoff)) = v;
        }
    }
}

// ---------------------------------------------------------------------------
extern "C" void kernel_launch(void* const* d_in, const int* in_sizes, int n_in,
                              void* d_out, int out_size, void* d_ws, size_t ws_size,
                              hipStream_t stream) {
    const float* x = (const float*)d_in[0];
    const float* mem = (const float*)d_in[1];
    float* out = (float*)d_out;
    char* ws = (char*)d_ws;

    unsigned short* Et = (unsigned short*)(ws);                // 16,777,216 B
    unsigned short* Bt = (unsigned short*)(ws + 16777216);     //    147,456 B
    float* S   = (float*)(ws + 16924672);                      //    524,288 B
    float* Zinv = (float*)(ws + 17448960);                     //    524,288 B

    prep_b<<<576, 128, 0, stream>>>(mem, Bt);
    exp_tr<<<1024, 256, 0, stream>>>(x, Et, S);
    boxz<<<512, 256, 0, stream>>>(S, Zinv);
    conv_mfma<<<2048, 256, 0, stream>>>(Et, Bt, Zinv, out);
}